// Round 1
// baseline (613.352 us; speedup 1.0000x reference)
//
#include <hip/hip_runtime.h>
#include <math.h>

#define BS 32
#define NV 512
#define NHEAD 8
#define FHID 16
#define FOUT 64
#define NTYPE 3
#define NEG_SLOPE 0.2f

// d_out float offsets: scores(32*2), v_sim_mul(32*64), attn1(32*8*512*512)
#define OUT_SCORES 0
#define OUT_VSIM   64
#define OUT_ATTN   2112

__device__ __forceinline__ float wave_red_max(float v) {
#pragma unroll
    for (int m = 1; m < 64; m <<= 1) v = fmaxf(v, __shfl_xor(v, m));
    return v;
}
__device__ __forceinline__ float wave_red_sum(float v) {
#pragma unroll
    for (int m = 1; m < 64; m <<= 1) v += __shfl_xor(v, m);
    return v;
}

// ---------------------------------------------------------------------------
// Kernel A: layer-1 type-gathered transform.
// grid = BS*NV blocks, 128 threads (8 heads x 16 outs).
// h_prime1[(b*8+h)*NV+n][o] = emb(64) @ w1[type,h](64x16)
// as1/ad1[(b*8+h)*NV+n] = sum_o tanh(hp)*a_{src,dst}1[h,o]
// ---------------------------------------------------------------------------
__global__ __launch_bounds__(128) void gat1_transform(
    const float* __restrict__ features, const float* __restrict__ line_emb,
    const int* __restrict__ v_types, const float* __restrict__ w1,
    const float* __restrict__ a_src1, const float* __restrict__ a_dst1,
    float* __restrict__ hp1, float* __restrict__ as1, float* __restrict__ ad1)
{
    int node = blockIdx.x;            // b*NV + n
    int b = node >> 9, n = node & (NV - 1);
    __shared__ float emb[64];
    int tid = threadIdx.x;
    if (tid < 32)      emb[tid] = features[node * 32 + tid];
    else if (tid < 64) emb[tid] = line_emb[node * 32 + (tid - 32)];
    __syncthreads();

    int h = tid >> 4, o = tid & 15;
    int tt = v_types[node];
    const float* wp = w1 + ((size_t)(tt * NHEAD + h) * 64) * FHID + o;
    float acc = 0.f;
#pragma unroll
    for (int k = 0; k < 64; ++k) acc += emb[k] * wp[k * FHID];

    hp1[((size_t)(b * NHEAD + h) * NV + n) * FHID + o] = acc;

    float th = tanhf(acc);
    float ps = th * a_src1[h * FHID + o];
    float pd = th * a_dst1[h * FHID + o];
#pragma unroll
    for (int m = 1; m < 16; m <<= 1) { ps += __shfl_xor(ps, m); pd += __shfl_xor(pd, m); }
    if (o == 0) {
        as1[(size_t)(b * NHEAD + h) * NV + n] = ps;
        ad1[(size_t)(b * NHEAD + h) * NV + n] = pd;
    }
}

// ---------------------------------------------------------------------------
// Kernel B: layer-1 attention + softmax + attn write + PV + (bias,ELU,reshape)
// grid = BS*NHEAD*NV/4 blocks, 256 threads (4 waves, one attn row each).
// ---------------------------------------------------------------------------
#define ROWS_PB 4
__global__ __launch_bounds__(256) void gat1_attn(
    const float* __restrict__ hp1, const float* __restrict__ as1,
    const float* __restrict__ ad1, const int* __restrict__ adj,
    const float* __restrict__ b1,
    float* __restrict__ attn_out, float* __restrict__ x1)
{
    __shared__ float hp[NV * 17];        // padded: stride 17 breaks 16-stride conflicts
    __shared__ float p_lds[ROWS_PB][NV];

    int bh = blockIdx.x / (NV / ROWS_PB);       // b*8+h
    int i0 = (blockIdx.x % (NV / ROWS_PB)) * ROWS_PB;
    int b = bh >> 3, h = bh & 7;
    int tid = threadIdx.x;

    // stage h_prime tile (512 x 16) into LDS with padded rows
    const float* src = hp1 + (size_t)bh * NV * FHID;
    for (int e = tid; e < NV * FHID; e += 256)
        hp[(e >> 4) * 17 + (e & 15)] = src[e];
    __syncthreads();

    int wave = tid >> 6, lane = tid & 63;
    int i = i0 + wave;

    float a_si = as1[(size_t)bh * NV + i];
    const float* adp = ad1 + (size_t)bh * NV;
    const int* adjrow = adj + ((size_t)b * NV + i) * NV;

    float e[8];
    float m = -INFINITY;
#pragma unroll
    for (int k = 0; k < 8; ++k) {
        int j = lane + 64 * k;
        float s = a_si + adp[j];
        s = (s >= 0.f) ? s : NEG_SLOPE * s;
        s = (adjrow[j] > 0) ? s : -INFINITY;
        e[k] = s;
        m = fmaxf(m, s);
    }
    m = wave_red_max(m);
    float sum = 0.f;
#pragma unroll
    for (int k = 0; k < 8; ++k) {
        float p = __expf(e[k] - m);
        e[k] = p;
        sum += p;
    }
    sum = wave_red_sum(sum);
    float inv = 1.f / sum;

    float* arow = attn_out + ((size_t)bh * NV + i) * NV;
#pragma unroll
    for (int k = 0; k < 8; ++k) {
        int j = lane + 64 * k;
        float p = e[k] * inv;
        arow[j] = p;              // coalesced 64-wide stores
        p_lds[wave][j] = p;       // wave-local, no barrier needed
    }

    // PV: lane = (o, g) with o<16, g<4. Each lane sums 128 j's (staggered to
    // spread banks), then 2-step shuffle reduce across the 4 g-groups.
    int o = lane & 15, g = lane >> 4;
    float acc = 0.f;
#pragma unroll 8
    for (int jj = 0; jj < 128; ++jj) {
        int j = g * 128 + ((jj + 8 * g) & 127);
        acc += p_lds[wave][j] * hp[j * 17 + o];
    }
    acc += __shfl_xor(acc, 16);
    acc += __shfl_xor(acc, 32);
    if (g == 0) {
        float v = acc + b1[o];
        v = (v > 0.f) ? v : (__expf(v) - 1.f);          // ELU
        x1[((size_t)b * NV + i) * (NHEAD * FHID) + h * FHID + o] = v;
    }
}

// ---------------------------------------------------------------------------
// Kernel C: layer-2 type-gathered transform. grid = BS*NV, 64 threads.
// hp2[node][o] = x1[node](128) @ w2[type](128x64); as2/ad2 dots of tanh.
// ---------------------------------------------------------------------------
__global__ __launch_bounds__(64) void gat2_transform(
    const float* __restrict__ x1, const int* __restrict__ v_types,
    const float* __restrict__ w2, const float* __restrict__ a_src2,
    const float* __restrict__ a_dst2,
    float* __restrict__ hp2, float* __restrict__ as2, float* __restrict__ ad2)
{
    int node = blockIdx.x;
    __shared__ float xin[128];
    int tid = threadIdx.x;
    xin[tid]      = x1[(size_t)node * 128 + tid];
    xin[tid + 64] = x1[(size_t)node * 128 + 64 + tid];
    __syncthreads();

    int tt = v_types[node];
    const float* wp = w2 + (size_t)tt * 128 * 64 + tid;
    float acc = 0.f;
#pragma unroll
    for (int f = 0; f < 128; ++f) acc += xin[f] * wp[f * 64];

    hp2[(size_t)node * 64 + tid] = acc;
    float th = tanhf(acc);
    float ps = wave_red_sum(th * a_src2[tid]);
    float pd = wave_red_sum(th * a_dst2[tid]);
    if (tid == 0) { as2[node] = ps; ad2[node] = pd; }
}

// ---------------------------------------------------------------------------
// Kernel D: layer-2 attention only for rows 0,1 + ELU + v_sim + MLP + logsoftmax
// grid = BS, 256 threads. Waves 0/1 handle rows 0/1.
// ---------------------------------------------------------------------------
__global__ __launch_bounds__(256) void head_kernel(
    const float* __restrict__ hp2, const float* __restrict__ as2,
    const float* __restrict__ ad2, const int* __restrict__ adj,
    const float* __restrict__ b2,
    const float* __restrict__ fc1_w, const float* __restrict__ fc1_b,
    const float* __restrict__ fc2_w, const float* __restrict__ fc2_b,
    const float* __restrict__ fc3_w, const float* __restrict__ fc3_b,
    float* __restrict__ d_out)
{
    int b = blockIdx.x;
    __shared__ float lr[2][64];
    __shared__ float vsim[64];
    __shared__ float v1[192];
    __shared__ float v2[64];
    int tid = threadIdx.x, wave = tid >> 6, lane = tid & 63;

    if (wave < 2) {
        int i = wave;
        float a_si = as2[(size_t)b * NV + i];
        const float* adp = ad2 + (size_t)b * NV;
        const int* adjrow = adj + ((size_t)b * NV + i) * NV;
        float e[8]; float m = -INFINITY;
#pragma unroll
        for (int k = 0; k < 8; ++k) {
            int j = lane + 64 * k;
            float s = a_si + adp[j];
            s = (s >= 0.f) ? s : NEG_SLOPE * s;
            s = (adjrow[j] > 0) ? s : -INFINITY;
            e[k] = s; m = fmaxf(m, s);
        }
        m = wave_red_max(m);
        float sum = 0.f;
#pragma unroll
        for (int k = 0; k < 8; ++k) { e[k] = __expf(e[k] - m); sum += e[k]; }
        sum = wave_red_sum(sum);
        float inv = 1.f / sum;

        float acc[64];
#pragma unroll
        for (int o = 0; o < 64; ++o) acc[o] = 0.f;
        for (int k = 0; k < 8; ++k) {
            int j = lane + 64 * k;
            float p = e[k] * inv;
            const float* hrow = hp2 + ((size_t)b * NV + j) * 64;
#pragma unroll
            for (int o = 0; o < 64; ++o) acc[o] += p * hrow[o];
        }
#pragma unroll
        for (int o = 0; o < 64; ++o) acc[o] = wave_red_sum(acc[o]);
        if (lane == 0) {
#pragma unroll
            for (int o = 0; o < 64; ++o) {
                float v = acc[o] + b2[o];
                v = (v > 0.f) ? v : (__expf(v) - 1.f);   // ELU
                lr[i][o] = v;
            }
        }
    }
    __syncthreads();

    if (tid < 64) {
        float v = lr[0][tid] * lr[1][tid];
        vsim[tid] = v;
        d_out[OUT_VSIM + (size_t)b * 64 + tid] = v;
    }
    __syncthreads();
    if (tid < 192) {
        float a = fc1_b[tid];
        for (int k = 0; k < 64; ++k) a += vsim[k] * fc1_w[k * 192 + tid];
        v1[tid] = fmaxf(a, 0.f);
    }
    __syncthreads();
    if (tid < 64) {
        float a = fc2_b[tid];
        for (int k = 0; k < 192; ++k) a += v1[k] * fc2_w[k * 64 + tid];
        v2[tid] = fmaxf(a, 0.f);
    }
    __syncthreads();
    if (tid == 0) {
        float s0 = fc3_b[0], s1 = fc3_b[1];
        for (int k = 0; k < 64; ++k) { s0 += v2[k] * fc3_w[k * 2]; s1 += v2[k] * fc3_w[k * 2 + 1]; }
        float mm = fmaxf(s0, s1);
        float l = logf(__expf(s0 - mm) + __expf(s1 - mm));
        d_out[(size_t)b * 2 + 0] = s0 - mm - l;
        d_out[(size_t)b * 2 + 1] = s1 - mm - l;
    }
}

// ---------------------------------------------------------------------------
extern "C" void kernel_launch(void* const* d_in, const int* in_sizes, int n_in,
                              void* d_out, int out_size, void* d_ws, size_t ws_size,
                              hipStream_t stream) {
    const float* features = (const float*)d_in[0];
    const int*   adj      = (const int*)d_in[1];
    // d_in[2]=bs, d_in[3]=num_v, d_in[4]=svm_features  (unused)
    const float* line_emb = (const float*)d_in[5];
    const int*   v_types  = (const int*)d_in[6];
    const float* w1       = (const float*)d_in[7];
    const float* a_src1   = (const float*)d_in[8];
    const float* a_dst1   = (const float*)d_in[9];
    const float* b1       = (const float*)d_in[10];
    const float* w2       = (const float*)d_in[11];
    const float* a_src2   = (const float*)d_in[12];
    const float* a_dst2   = (const float*)d_in[13];
    const float* b2       = (const float*)d_in[14];
    const float* fc1_w    = (const float*)d_in[15];
    const float* fc1_b    = (const float*)d_in[16];
    const float* fc2_w    = (const float*)d_in[17];
    const float* fc2_b    = (const float*)d_in[18];
    const float* fc3_w    = (const float*)d_in[19];
    const float* fc3_b    = (const float*)d_in[20];

    float* out = (float*)d_out;
    float* ws = (float*)d_ws;
    float* hp1 = ws;                                   // 32*8*512*16 = 2097152
    float* as1 = hp1 + (size_t)BS * NHEAD * NV * FHID; // 131072
    float* ad1 = as1 + (size_t)BS * NHEAD * NV;
    float* x1  = ad1 + (size_t)BS * NHEAD * NV;        // 32*512*128 = 2097152
    float* hp2 = x1 + (size_t)BS * NV * NHEAD * FHID;  // 32*512*64 = 1048576
    float* as2 = hp2 + (size_t)BS * NV * FOUT;         // 16384
    float* ad2 = as2 + (size_t)BS * NV;

    hipLaunchKernelGGL(gat1_transform, dim3(BS * NV), dim3(128), 0, stream,
                       features, line_emb, v_types, w1, a_src1, a_dst1,
                       hp1, as1, ad1);

    hipLaunchKernelGGL(gat1_attn, dim3(BS * NHEAD * NV / ROWS_PB), dim3(256), 0, stream,
                       hp1, as1, ad1, adj, b1, out + OUT_ATTN, x1);

    hipLaunchKernelGGL(gat2_transform, dim3(BS * NV), dim3(64), 0, stream,
                       x1, v_types, w2, a_src2, a_dst2, hp2, as2, ad2);

    hipLaunchKernelGGL(head_kernel, dim3(BS), dim3(256), 0, stream,
                       hp2, as2, ad2, adj, b2,
                       fc1_w, fc1_b, fc2_w, fc2_b, fc3_w, fc3_b, d_out ? (float*)d_out : out);
}

// Round 2
// 516.092 us; speedup vs baseline: 1.1885x; 1.1885x over previous
//
#include <hip/hip_runtime.h>
#include <math.h>

#define BS 32
#define NV 512
#define NHEAD 8
#define FHID 16
#define FOUT 64
#define NTYPE 3
#define NEG_SLOPE 0.2f

// d_out float offsets: scores(32*2), v_sim_mul(32*64), attn1(32*8*512*512)
#define OUT_VSIM   64
#define OUT_ATTN   2112

__device__ __forceinline__ float wave_red_max(float v) {
#pragma unroll
    for (int m = 1; m < 64; m <<= 1) v = fmaxf(v, __shfl_xor(v, m));
    return v;
}
__device__ __forceinline__ float wave_red_sum(float v) {
#pragma unroll
    for (int m = 1; m < 64; m <<= 1) v += __shfl_xor(v, m);
    return v;
}

// ---------------------------------------------------------------------------
// Kernel W: transpose w2 (3,128,64) -> w2T (3,64,128)
// ---------------------------------------------------------------------------
__global__ __launch_bounds__(256) void transpose_w2(const float* __restrict__ w2,
                                                    float* __restrict__ w2T) {
    int idx = blockIdx.x * 256 + threadIdx.x;
    if (idx < 3 * 64 * 128) {
        int t = idx >> 13, rem = idx & 8191, o = rem >> 7, f = rem & 127;
        w2T[idx] = w2[((size_t)t * 128 + f) * 64 + o];
    }
}

// ---------------------------------------------------------------------------
// Kernel A: layer-1 type-gathered transform.
// grid = BS*NHEAD*(NV/64) = 2048 blocks, 256 threads.
// Block = (b, h, chunk of 64 nodes). Stage wT[3][16][68] + emb[64][68] in LDS.
// ---------------------------------------------------------------------------
__global__ __launch_bounds__(256) void gat1_transform_v2(
    const float* __restrict__ features, const float* __restrict__ line_emb,
    const int* __restrict__ v_types, const float* __restrict__ w1,
    const float* __restrict__ a_src1, const float* __restrict__ a_dst1,
    float* __restrict__ hp1, float* __restrict__ as1, float* __restrict__ ad1)
{
    int chunk = blockIdx.x & 7;
    int bh = blockIdx.x >> 3;
    int b = bh >> 3, h = bh & 7;
    int nb = chunk * 64;
    __shared__ float wT[3 * 16 * 68];   // [t][o][k], row stride 68 (16B-aligned)
    __shared__ float emb[64 * 68];      // [n][k], row stride 68
    __shared__ int vt[64];
    int tid = threadIdx.x;

    for (int e = tid; e < 3 * 16 * 64; e += 256) {
        int t = e >> 10, rem = e & 1023, o = rem >> 6, k = rem & 63;
        wT[(t * 16 + o) * 68 + k] = w1[(((size_t)t * 8 + h) * 64 + k) * 16 + o];
    }
    int node0 = b * NV + nb;
    for (int e = tid; e < 64 * 64; e += 256) {
        int n = e >> 6, k = e & 63;
        float v = (k < 32) ? features[(size_t)(node0 + n) * 32 + k]
                           : line_emb[(size_t)(node0 + n) * 32 + (k - 32)];
        emb[n * 68 + k] = v;
    }
    if (tid < 64) vt[tid] = v_types[node0 + tid];
    __syncthreads();

    int o = tid & 15, nl = tid >> 4;
    float asw = a_src1[h * 16 + o], adw = a_dst1[h * 16 + o];
#pragma unroll
    for (int sub = 0; sub < 4; ++sub) {
        int n = sub * 16 + nl;
        int tt = vt[n];
        const float4* ep = (const float4*)&emb[n * 68];
        const float4* wp = (const float4*)&wT[(tt * 16 + o) * 68];
        float acc = 0.f;
#pragma unroll
        for (int kc = 0; kc < 16; ++kc) {
            float4 ev = ep[kc], wv = wp[kc];
            acc += ev.x * wv.x + ev.y * wv.y + ev.z * wv.z + ev.w * wv.w;
        }
        hp1[((size_t)bh * NV + nb + n) * FHID + o] = acc;
        float th = tanhf(acc);
        float ps = th * asw, pd = th * adw;
#pragma unroll
        for (int m = 1; m < 16; m <<= 1) { ps += __shfl_xor(ps, m); pd += __shfl_xor(pd, m); }
        if (o == 0) {
            as1[(size_t)bh * NV + nb + n] = ps;
            ad1[(size_t)bh * NV + nb + n] = pd;
        }
    }
}

// ---------------------------------------------------------------------------
// Kernel B: layer-1 attention. 8 rows/block, 256 threads.
// grid = BS*NHEAD*(NV/8) = 16384 blocks.
// ---------------------------------------------------------------------------
#define ROWS_PB 8
#define HPT_STRIDE 524   // mod 32 == 12 -> max 2-way bank aliasing over 16 o-rows

__global__ __launch_bounds__(256) void gat1_attn_v2(
    const float* __restrict__ hp1, const float* __restrict__ as1,
    const float* __restrict__ ad1, const int* __restrict__ adj,
    const float* __restrict__ b1,
    float* __restrict__ attn_out, float* __restrict__ x1)
{
    __shared__ float hpT[16 * HPT_STRIDE];      // [o][n] transposed h_prime
    __shared__ float p_lds[ROWS_PB][NV];
    __shared__ float partial[4 * ROWS_PB * 16]; // [wave][r][o]

    int bh = blockIdx.x >> 6;                   // b*8+h
    int i0 = (blockIdx.x & 63) * ROWS_PB;
    int b = bh >> 3, h = bh & 7;
    int tid = threadIdx.x;

    // stage h_prime (512x16 row-major in global) transposed into LDS
    const float* src = hp1 + (size_t)bh * NV * FHID;
    for (int e = tid; e < NV * FHID; e += 256)
        hpT[(e & 15) * HPT_STRIDE + (e >> 4)] = src[e];

    int wave = tid >> 6, lane = tid & 63;

    // softmax: each wave handles 2 rows; lane owns 8 consecutive j
    const float4* adp4 = (const float4*)(ad1 + (size_t)bh * NV);
    float4 d0 = adp4[lane * 2], d1 = adp4[lane * 2 + 1];
    const int* adjb = adj + (size_t)b * NV * NV;

#pragma unroll
    for (int rr = 0; rr < 2; ++rr) {
        int rl = wave * 2 + rr;
        int i = i0 + rl;
        float a_si = as1[(size_t)bh * NV + i];
        const int4* mrow = (const int4*)(adjb + (size_t)i * NV);
        int4 m0 = mrow[lane * 2], m1 = mrow[lane * 2 + 1];
        float s[8];
        s[0] = a_si + d0.x; s[1] = a_si + d0.y; s[2] = a_si + d0.z; s[3] = a_si + d0.w;
        s[4] = a_si + d1.x; s[5] = a_si + d1.y; s[6] = a_si + d1.z; s[7] = a_si + d1.w;
        int mk[8] = {m0.x, m0.y, m0.z, m0.w, m1.x, m1.y, m1.z, m1.w};
        float mx = -INFINITY;
#pragma unroll
        for (int k = 0; k < 8; ++k) {
            float v = s[k];
            v = (v >= 0.f) ? v : NEG_SLOPE * v;
            v = (mk[k] > 0) ? v : -INFINITY;
            s[k] = v;
            mx = fmaxf(mx, v);
        }
        mx = wave_red_max(mx);
        float sum = 0.f;
#pragma unroll
        for (int k = 0; k < 8; ++k) { s[k] = __expf(s[k] - mx); sum += s[k]; }
        sum = wave_red_sum(sum);
        float inv = 1.f / sum;
        float4 pa = {s[0] * inv, s[1] * inv, s[2] * inv, s[3] * inv};
        float4 pb = {s[4] * inv, s[5] * inv, s[6] * inv, s[7] * inv};
        float4* arow = (float4*)(attn_out + ((size_t)bh * NV + i) * NV);
        arow[lane * 2] = pa;
        arow[lane * 2 + 1] = pb;
        float4* pl = (float4*)&p_lds[rl][0];
        pl[lane * 2] = pa;
        pl[lane * 2 + 1] = pb;
    }
    __syncthreads();

    // PV: lane = (o, jg). jg owns 32 j's (8 float4 chunks), accumulates all 8 rows.
    int o = tid & 15, jg = tid >> 4;
    int jg3 = jg & 3;
    float acc[ROWS_PB];
#pragma unroll
    for (int r = 0; r < ROWS_PB; ++r) acc[r] = 0.f;
    const float* hbase = &hpT[o * HPT_STRIDE + jg * 32];
    const float* pbase = &p_lds[0][jg * 32];
#pragma unroll
    for (int c = 0; c < 8; ++c) {
        int ce = c ^ (jg3 << 1);                     // bank-stagger across jg groups
        float4 h4 = *(const float4*)(hbase + ce * 4);
        const float* pb = pbase + ce * 4;
#pragma unroll
        for (int r = 0; r < ROWS_PB; ++r) {
            float4 p4 = *(const float4*)(pb + r * NV);
            acc[r] += p4.x * h4.x + p4.y * h4.y + p4.z * h4.z + p4.w * h4.w;
        }
    }
#pragma unroll
    for (int r = 0; r < ROWS_PB; ++r) {
        acc[r] += __shfl_xor(acc[r], 16);
        acc[r] += __shfl_xor(acc[r], 32);
    }
    if ((lane >> 4) == 0) {
#pragma unroll
        for (int r = 0; r < ROWS_PB; ++r)
            partial[(wave * ROWS_PB + r) * 16 + o] = acc[r];
    }
    __syncthreads();

    if (tid < 128) {
        int r = tid >> 4, oo = tid & 15;
        float v = partial[r * 16 + oo] + partial[128 + r * 16 + oo]
                + partial[256 + r * 16 + oo] + partial[384 + r * 16 + oo] + b1[oo];
        v = (v > 0.f) ? v : (__expf(v) - 1.f);       // ELU
        x1[((size_t)b * NV + i0 + r) * (NHEAD * FHID) + h * FHID + oo] = v;
    }
}

// ---------------------------------------------------------------------------
// Kernel C: layer-2 transform. grid = BS*(NV/32) = 512 blocks, 256 threads.
// ---------------------------------------------------------------------------
__global__ __launch_bounds__(256) void gat2_transform_v2(
    const float* __restrict__ x1, const int* __restrict__ v_types,
    const float* __restrict__ w2T, const float* __restrict__ a_src2,
    const float* __restrict__ a_dst2,
    float* __restrict__ hp2, float* __restrict__ as2, float* __restrict__ ad2)
{
    int blk = blockIdx.x;
    int b = blk >> 4, chunk = blk & 15;
    int node0 = b * NV + chunk * 32;
    __shared__ float xin[32 * 132];   // row stride 132 (16B-aligned)
    __shared__ int vt[32];
    int tid = threadIdx.x;
    for (int e = tid; e < 32 * 128; e += 256) {
        int n = e >> 7, f = e & 127;
        xin[n * 132 + f] = x1[(size_t)(node0 + n) * 128 + f];
    }
    if (tid < 32) vt[tid] = v_types[node0 + tid];
    __syncthreads();

    int o = tid & 63, nl = tid >> 6;
    float asw = a_src2[o], adw = a_dst2[o];
#pragma unroll 2
    for (int pass = 0; pass < 8; ++pass) {
        int n = pass * 4 + nl;
        int tt = vt[n];
        const float4* xp = (const float4*)&xin[n * 132];
        const float4* wp = (const float4*)(w2T + ((size_t)tt * 64 + o) * 128);
        float acc = 0.f;
#pragma unroll
        for (int fc = 0; fc < 32; ++fc) {
            float4 xv = xp[fc], wv = wp[fc];
            acc += xv.x * wv.x + xv.y * wv.y + xv.z * wv.z + xv.w * wv.w;
        }
        hp2[(size_t)(node0 + n) * 64 + o] = acc;
        float th = tanhf(acc);
        float ps = wave_red_sum(th * asw);
        float pd = wave_red_sum(th * adw);
        if (o == 0) { as2[node0 + n] = ps; ad2[node0 + n] = pd; }
    }
}

// ---------------------------------------------------------------------------
// Kernel D: layer-2 attention rows 0/1 + ELU + v_sim + MLP + log_softmax.
// grid = BS, 512 threads.
// ---------------------------------------------------------------------------
__global__ __launch_bounds__(512) void head_v2(
    const float* __restrict__ hp2, const float* __restrict__ as2,
    const float* __restrict__ ad2, const int* __restrict__ adj,
    const float* __restrict__ b2,
    const float* __restrict__ fc1_w, const float* __restrict__ fc1_b,
    const float* __restrict__ fc2_w, const float* __restrict__ fc2_b,
    const float* __restrict__ fc3_w, const float* __restrict__ fc3_b,
    float* __restrict__ d_out)
{
    int b = blockIdx.x;
    __shared__ float p2[2][NV];
    __shared__ float partial[2 * 4 * 64];
    __shared__ float lr[2][64];
    __shared__ float vsim[64];
    __shared__ float v1[192];
    __shared__ float v2s[64];
    int tid = threadIdx.x, wave = tid >> 6, lane = tid & 63;

    if ((wave & 3) == 0) {          // waves 0 and 4 -> rows 0 and 1
        int i = wave >> 2;
        float a_si = as2[(size_t)b * NV + i];
        const float4* adp4 = (const float4*)(ad2 + (size_t)b * NV);
        float4 d0 = adp4[lane * 2], d1 = adp4[lane * 2 + 1];
        const int4* mrow = (const int4*)(adj + ((size_t)b * NV + i) * NV);
        int4 m0 = mrow[lane * 2], m1 = mrow[lane * 2 + 1];
        float s[8];
        s[0] = a_si + d0.x; s[1] = a_si + d0.y; s[2] = a_si + d0.z; s[3] = a_si + d0.w;
        s[4] = a_si + d1.x; s[5] = a_si + d1.y; s[6] = a_si + d1.z; s[7] = a_si + d1.w;
        int mk[8] = {m0.x, m0.y, m0.z, m0.w, m1.x, m1.y, m1.z, m1.w};
        float mx = -INFINITY;
#pragma unroll
        for (int k = 0; k < 8; ++k) {
            float v = s[k];
            v = (v >= 0.f) ? v : NEG_SLOPE * v;
            v = (mk[k] > 0) ? v : -INFINITY;
            s[k] = v; mx = fmaxf(mx, v);
        }
        mx = wave_red_max(mx);
        float sum = 0.f;
#pragma unroll
        for (int k = 0; k < 8; ++k) { s[k] = __expf(s[k] - mx); sum += s[k]; }
        sum = wave_red_sum(sum);
        float inv = 1.f / sum;
#pragma unroll
        for (int k = 0; k < 8; ++k) p2[i][lane * 8 + k] = s[k] * inv;
    }
    __syncthreads();

    // PV: thread = (i, g, o); 128 j's each
    {
        int i = tid >> 8, g = (tid >> 6) & 3, o = tid & 63;
        float acc = 0.f;
        const float* hb = hp2 + ((size_t)b * NV + g * 128) * 64 + o;
#pragma unroll 8
        for (int jj = 0; jj < 128; ++jj)
            acc += p2[i][g * 128 + jj] * hb[(size_t)jj * 64];
        partial[(i * 4 + g) * 64 + o] = acc;
    }
    __syncthreads();
    if (tid < 128) {
        int i = tid >> 6, o = tid & 63;
        float v = partial[i * 256 + o] + partial[i * 256 + 64 + o]
                + partial[i * 256 + 128 + o] + partial[i * 256 + 192 + o] + b2[o];
        v = (v > 0.f) ? v : (__expf(v) - 1.f);      // ELU
        lr[i][o] = v;
    }
    __syncthreads();
    if (tid < 64) {
        float v = lr[0][tid] * lr[1][tid];
        vsim[tid] = v;
        d_out[OUT_VSIM + (size_t)b * 64 + tid] = v;
    }
    __syncthreads();
    if (tid < 192) {
        float a = fc1_b[tid];
        for (int k = 0; k < 64; ++k) a += vsim[k] * fc1_w[k * 192 + tid];
        v1[tid] = fmaxf(a, 0.f);
    }
    __syncthreads();
    if (tid < 64) {
        float a = fc2_b[tid];
        for (int k = 0; k < 192; ++k) a += v1[k] * fc2_w[k * 64 + tid];
        v2s[tid] = fmaxf(a, 0.f);
    }
    __syncthreads();
    if (tid == 0) {
        float s0 = fc3_b[0], s1 = fc3_b[1];
        for (int k = 0; k < 64; ++k) { s0 += v2s[k] * fc3_w[k * 2]; s1 += v2s[k] * fc3_w[k * 2 + 1]; }
        float mm = fmaxf(s0, s1);
        float l = logf(__expf(s0 - mm) + __expf(s1 - mm));
        d_out[(size_t)b * 2 + 0] = s0 - mm - l;
        d_out[(size_t)b * 2 + 1] = s1 - mm - l;
    }
}

// ---------------------------------------------------------------------------
extern "C" void kernel_launch(void* const* d_in, const int* in_sizes, int n_in,
                              void* d_out, int out_size, void* d_ws, size_t ws_size,
                              hipStream_t stream) {
    const float* features = (const float*)d_in[0];
    const int*   adj      = (const int*)d_in[1];
    const float* line_emb = (const float*)d_in[5];
    const int*   v_types  = (const int*)d_in[6];
    const float* w1       = (const float*)d_in[7];
    const float* a_src1   = (const float*)d_in[8];
    const float* a_dst1   = (const float*)d_in[9];
    const float* b1       = (const float*)d_in[10];
    const float* w2       = (const float*)d_in[11];
    const float* a_src2   = (const float*)d_in[12];
    const float* a_dst2   = (const float*)d_in[13];
    const float* b2       = (const float*)d_in[14];
    const float* fc1_w    = (const float*)d_in[15];
    const float* fc1_b    = (const float*)d_in[16];
    const float* fc2_w    = (const float*)d_in[17];
    const float* fc2_b    = (const float*)d_in[18];
    const float* fc3_w    = (const float*)d_in[19];
    const float* fc3_b    = (const float*)d_in[20];

    float* out = (float*)d_out;
    float* ws = (float*)d_ws;
    float* hp1 = ws;                                   // 32*8*512*16 = 2097152
    float* as1 = hp1 + (size_t)BS * NHEAD * NV * FHID;
    float* ad1 = as1 + (size_t)BS * NHEAD * NV;
    float* x1  = ad1 + (size_t)BS * NHEAD * NV;        // 2097152
    float* hp2 = x1 + (size_t)BS * NV * NHEAD * FHID;  // 1048576
    float* as2 = hp2 + (size_t)BS * NV * FOUT;
    float* ad2 = as2 + (size_t)BS * NV;
    float* w2T = ad2 + (size_t)BS * NV;                // 3*64*128 = 24576

    hipLaunchKernelGGL(transpose_w2, dim3(96), dim3(256), 0, stream, w2, w2T);

    hipLaunchKernelGGL(gat1_transform_v2, dim3(BS * NHEAD * (NV / 64)), dim3(256), 0, stream,
                       features, line_emb, v_types, w1, a_src1, a_dst1, hp1, as1, ad1);

    hipLaunchKernelGGL(gat1_attn_v2, dim3(BS * NHEAD * (NV / ROWS_PB)), dim3(256), 0, stream,
                       hp1, as1, ad1, adj, b1, out + OUT_ATTN, x1);

    hipLaunchKernelGGL(gat2_transform_v2, dim3(BS * (NV / 32)), dim3(256), 0, stream,
                       x1, v_types, w2T, a_src2, a_dst2, hp2, as2, ad2);

    hipLaunchKernelGGL(head_v2, dim3(BS), dim3(512), 0, stream,
                       hp2, as2, ad2, adj, b2,
                       fc1_w, fc1_b, fc2_w, fc2_b, fc3_w, fc3_b, out);
}

// Round 4
// 492.536 us; speedup vs baseline: 1.2453x; 1.0478x over previous
//
#include <hip/hip_runtime.h>
#include <math.h>

#define BS 32
#define NV 512
#define NHEAD 8
#define FHID 16
#define FOUT 64
#define NTYPE 3
#define NEG_SLOPE 0.2f

// d_out float offsets: scores(32*2), v_sim_mul(32*64), attn1(32*8*512*512)
#define OUT_VSIM   64
#define OUT_ATTN   2112

typedef __attribute__((ext_vector_type(8))) short bh8;
typedef __attribute__((ext_vector_type(4))) float f32x4;

__device__ __forceinline__ float wave_red_max(float v) {
#pragma unroll
    for (int m = 1; m < 64; m <<= 1) v = fmaxf(v, __shfl_xor(v, m));
    return v;
}
__device__ __forceinline__ float wave_red_sum(float v) {
#pragma unroll
    for (int m = 1; m < 64; m <<= 1) v += __shfl_xor(v, m);
    return v;
}
__device__ __forceinline__ ushort f2bf(float x) {   // RNE fp32 -> bf16 bits
    union { float f; unsigned u; } v; v.f = x;
    return (ushort)((v.u + 0x7FFFu + ((v.u >> 16) & 1u)) >> 16);
}

// ---------------------------------------------------------------------------
// Kernel W: transpose w2 (3,128,64) -> w2T (3,64,128)
// ---------------------------------------------------------------------------
__global__ __launch_bounds__(256) void transpose_w2(const float* __restrict__ w2,
                                                    float* __restrict__ w2T) {
    int idx = blockIdx.x * 256 + threadIdx.x;
    if (idx < 3 * 64 * 128) {
        int t = idx >> 13, rem = idx & 8191, o = rem >> 7, f = rem & 127;
        w2T[idx] = w2[((size_t)t * 128 + f) * 64 + o];
    }
}

// ---------------------------------------------------------------------------
// Kernel A: layer-1 transform -> hpT_g[bh][o(16)][n(512)] fp32 (transposed),
// plus as1/ad1. grid = BS*NHEAD*8 = 2048 blocks, 256 threads.
// ---------------------------------------------------------------------------
__global__ __launch_bounds__(256) void gat1_transform_v3(
    const float* __restrict__ features, const float* __restrict__ line_emb,
    const int* __restrict__ v_types, const float* __restrict__ w1,
    const float* __restrict__ a_src1, const float* __restrict__ a_dst1,
    float* __restrict__ hpT_g, float* __restrict__ as1, float* __restrict__ ad1)
{
    int chunk = blockIdx.x & 7;
    int bh = blockIdx.x >> 3;
    int b = bh >> 3, h = bh & 7;
    int nb = chunk * 64;
    __shared__ float wT[3 * 16 * 68];   // [t][o][k]
    __shared__ float emb[64 * 68];      // [n][k]
    __shared__ float tpo[16 * 68];      // [o][n_local]
    __shared__ int vt[64];
    int tid = threadIdx.x;

    for (int e = tid; e < 3 * 16 * 64; e += 256) {
        int t = e >> 10, rem = e & 1023, o = rem >> 6, k = rem & 63;
        wT[(t * 16 + o) * 68 + k] = w1[(((size_t)t * 8 + h) * 64 + k) * 16 + o];
    }
    int node0 = b * NV + nb;
    for (int e = tid; e < 64 * 64; e += 256) {
        int n = e >> 6, k = e & 63;
        float v = (k < 32) ? features[(size_t)(node0 + n) * 32 + k]
                           : line_emb[(size_t)(node0 + n) * 32 + (k - 32)];
        emb[n * 68 + k] = v;
    }
    if (tid < 64) vt[tid] = v_types[node0 + tid];
    __syncthreads();

    int o = tid & 15, nl = tid >> 4;
    float asw = a_src1[h * 16 + o], adw = a_dst1[h * 16 + o];
#pragma unroll
    for (int sub = 0; sub < 4; ++sub) {
        int n = sub * 16 + nl;
        int tt = vt[n];
        const float4* ep = (const float4*)&emb[n * 68];
        const float4* wp = (const float4*)&wT[(tt * 16 + o) * 68];
        float acc = 0.f;
#pragma unroll
        for (int kc = 0; kc < 16; ++kc) {
            float4 ev = ep[kc], wv = wp[kc];
            acc += ev.x * wv.x + ev.y * wv.y + ev.z * wv.z + ev.w * wv.w;
        }
        tpo[o * 68 + n] = acc;
        float th = tanhf(acc);
        float ps = th * asw, pd = th * adw;
#pragma unroll
        for (int m = 1; m < 16; m <<= 1) { ps += __shfl_xor(ps, m); pd += __shfl_xor(pd, m); }
        if (o == 0) {
            as1[(size_t)bh * NV + nb + n] = ps;
            ad1[(size_t)bh * NV + nb + n] = pd;
        }
    }
    __syncthreads();
    // coalesced transposed write: thread = (o2, c)
    int o2 = tid >> 4, c = tid & 15;
    float4 v = *(const float4*)&tpo[o2 * 68 + c * 4];
    *(float4*)&hpT_g[((size_t)bh * 16 + o2) * NV + nb + c * 4] = v;
}

// ---------------------------------------------------------------------------
// Kernel B: layer-1 attention. 16 rows/block, 256 threads, MFMA PV.
// grid = BS*NHEAD*(NV/16) = 8192 blocks.
// ---------------------------------------------------------------------------
#define RPB 16
#define HS 520    // ushort row stride: 1040 B -> 2-way bank aliasing only (free)

__global__ __launch_bounds__(256) void gat1_attn_v3(
    const float* __restrict__ hpT_g, const float* __restrict__ as1,
    const float* __restrict__ ad1, const int* __restrict__ adj,
    const float* __restrict__ b1,
    float* __restrict__ attn_out, float* __restrict__ x1)
{
    __shared__ ushort hpb[16 * HS];         // bf16 H^T tile [o][n]
    __shared__ ushort pb[RPB * HS];         // bf16 P tile [row][j]
    __shared__ float partial[4][16][16];    // [wave][col(o)][row]

    int bh = blockIdx.x >> 5;               // b*8+h
    int i0 = (blockIdx.x & 31) * RPB;
    int b = bh >> 3, h = bh & 7;
    int tid = threadIdx.x;

    // stage H^T tile (fp32 -> bf16), coalesced float4 reads
    const float* src = hpT_g + (size_t)bh * 16 * NV;
#pragma unroll
    for (int k = 0; k < 8; ++k) {
        int flat = k * 1024 + tid * 4;
        float4 v = *(const float4*)(src + flat);
        int o = flat >> 9, n = flat & 511;
        ushort4 u; u.x = f2bf(v.x); u.y = f2bf(v.y); u.z = f2bf(v.z); u.w = f2bf(v.w);
        *(ushort4*)&hpb[o * HS + n] = u;
    }

    int wave = tid >> 6, lane = tid & 63;

    const float4* adp4 = (const float4*)(ad1 + (size_t)bh * NV);
    float4 d0 = adp4[lane * 2], d1 = adp4[lane * 2 + 1];
    const int* adjb = adj + (size_t)b * NV * NV;

    // softmax: wave w owns rows w*4 .. w*4+3; lane owns 8 consecutive j
#pragma unroll
    for (int rr = 0; rr < 4; ++rr) {
        int rl = wave * 4 + rr;
        int i = i0 + rl;
        float a_si = as1[(size_t)bh * NV + i];
        const int4* mrow = (const int4*)(adjb + (size_t)i * NV);
        int4 m0 = mrow[lane * 2], m1 = mrow[lane * 2 + 1];
        float s[8];
        s[0] = a_si + d0.x; s[1] = a_si + d0.y; s[2] = a_si + d0.z; s[3] = a_si + d0.w;
        s[4] = a_si + d1.x; s[5] = a_si + d1.y; s[6] = a_si + d1.z; s[7] = a_si + d1.w;
        int mk[8] = {m0.x, m0.y, m0.z, m0.w, m1.x, m1.y, m1.z, m1.w};
        float mx = -INFINITY;
#pragma unroll
        for (int k = 0; k < 8; ++k) {
            float v = s[k];
            v = (v >= 0.f) ? v : NEG_SLOPE * v;
            v = (mk[k] > 0) ? v : -INFINITY;
            s[k] = v;
            mx = fmaxf(mx, v);
        }
        mx = wave_red_max(mx);
        float sum = 0.f;
#pragma unroll
        for (int k = 0; k < 8; ++k) { s[k] = __expf(s[k] - mx); sum += s[k]; }
        sum = wave_red_sum(sum);
        float inv = 1.f / sum;
#pragma unroll
        for (int k = 0; k < 8; ++k) s[k] *= inv;

        // exact fp32 attn output (coalesced)
        float4* arow = (float4*)(attn_out + ((size_t)bh * NV + i) * NV);
        float4 pa = {s[0], s[1], s[2], s[3]};
        float4 pv = {s[4], s[5], s[6], s[7]};
        arow[lane * 2] = pa;
        arow[lane * 2 + 1] = pv;
        // bf16 P for MFMA
        ushort4 u0 = {f2bf(s[0]), f2bf(s[1]), f2bf(s[2]), f2bf(s[3])};
        ushort4 u1 = {f2bf(s[4]), f2bf(s[5]), f2bf(s[6]), f2bf(s[7])};
        *(ushort4*)&pb[rl * HS + lane * 8] = u0;
        *(ushort4*)&pb[rl * HS + lane * 8 + 4] = u1;
    }
    __syncthreads();

    // PV via MFMA: X[16x16] = P[16x512] @ H[512x16]; wave w does 4 K-chunks.
    // A-frag: lane holds P[lane&15][kc*32 + (lane>>4)*8 + 0..7]
    // B-frag: lane holds H[kc*32 + (lane>>4)*8 + 0..7][lane&15] = hpb[col][k..]
    int row16 = lane & 15, kg = lane >> 4;
    f32x4 acc = {0.f, 0.f, 0.f, 0.f};
#pragma unroll
    for (int c = 0; c < 4; ++c) {
        int k0 = (wave * 4 + c) * 32 + kg * 8;
        bh8 a = *(const bh8*)&pb[row16 * HS + k0];
        bh8 bf = *(const bh8*)&hpb[row16 * HS + k0];
        acc = __builtin_amdgcn_mfma_f32_16x16x32_bf16(a, bf, acc, 0, 0, 0);
    }
    // D layout: lane holds D[row=(lane>>4)*4+reg][col=lane&15]
    *(float4*)&partial[wave][row16][kg * 4] = *(float4*)&acc;
    __syncthreads();

    // combine 4 wave-partials + bias + ELU, write x1
    {
        int r = tid >> 4, o = tid & 15;
        float v = partial[0][o][r] + partial[1][o][r]
                + partial[2][o][r] + partial[3][o][r] + b1[o];
        v = (v > 0.f) ? v : (__expf(v) - 1.f);
        x1[((size_t)b * NV + i0 + r) * (NHEAD * FHID) + h * FHID + o] = v;
    }
}

// ---------------------------------------------------------------------------
// Kernel C: layer-2 transform. grid = BS*(NV/32) = 512 blocks, 256 threads.
// ---------------------------------------------------------------------------
__global__ __launch_bounds__(256) void gat2_transform_v2(
    const float* __restrict__ x1, const int* __restrict__ v_types,
    const float* __restrict__ w2T, const float* __restrict__ a_src2,
    const float* __restrict__ a_dst2,
    float* __restrict__ hp2, float* __restrict__ as2, float* __restrict__ ad2)
{
    int blk = blockIdx.x;
    int b = blk >> 4, chunk = blk & 15;
    int node0 = b * NV + chunk * 32;
    __shared__ float xin[32 * 132];
    __shared__ int vt[32];
    int tid = threadIdx.x;
    for (int e = tid; e < 32 * 128; e += 256) {
        int n = e >> 7, f = e & 127;
        xin[n * 132 + f] = x1[(size_t)(node0 + n) * 128 + f];
    }
    if (tid < 32) vt[tid] = v_types[node0 + tid];
    __syncthreads();

    int o = tid & 63, nl = tid >> 6;
    float asw = a_src2[o], adw = a_dst2[o];
#pragma unroll 2
    for (int pass = 0; pass < 8; ++pass) {
        int n = pass * 4 + nl;
        int tt = vt[n];
        const float4* xp = (const float4*)&xin[n * 132];
        const float4* wp = (const float4*)(w2T + ((size_t)tt * 64 + o) * 128);
        float acc = 0.f;
#pragma unroll
        for (int fc = 0; fc < 32; ++fc) {
            float4 xv = xp[fc], wv = wp[fc];
            acc += xv.x * wv.x + xv.y * wv.y + xv.z * wv.z + xv.w * wv.w;
        }
        hp2[(size_t)(node0 + n) * 64 + o] = acc;
        float th = tanhf(acc);
        float ps = wave_red_sum(th * asw);
        float pd = wave_red_sum(th * adw);
        if (o == 0) { as2[node0 + n] = ps; ad2[node0 + n] = pd; }
    }
}

// ---------------------------------------------------------------------------
// Kernel D: layer-2 attention rows 0/1 + ELU + v_sim + MLP + log_softmax.
// grid = BS, 512 threads.
// ---------------------------------------------------------------------------
__global__ __launch_bounds__(512) void head_v2(
    const float* __restrict__ hp2, const float* __restrict__ as2,
    const float* __restrict__ ad2, const int* __restrict__ adj,
    const float* __restrict__ b2,
    const float* __restrict__ fc1_w, const float* __restrict__ fc1_b,
    const float* __restrict__ fc2_w, const float* __restrict__ fc2_b,
    const float* __restrict__ fc3_w, const float* __restrict__ fc3_b,
    float* __restrict__ d_out)
{
    int b = blockIdx.x;
    __shared__ float p2[2][NV];
    __shared__ float partial[2 * 4 * 64];
    __shared__ float lr[2][64];
    __shared__ float vsim[64];
    __shared__ float v1[192];
    __shared__ float v2s[64];
    int tid = threadIdx.x, wave = tid >> 6, lane = tid & 63;

    if ((wave & 3) == 0) {          // waves 0 and 4 -> rows 0 and 1
        int i = wave >> 2;
        float a_si = as2[(size_t)b * NV + i];
        const float4* adp4 = (const float4*)(ad2 + (size_t)b * NV);
        float4 d0 = adp4[lane * 2], d1 = adp4[lane * 2 + 1];
        const int4* mrow = (const int4*)(adj + ((size_t)b * NV + i) * NV);
        int4 m0 = mrow[lane * 2], m1 = mrow[lane * 2 + 1];
        float s[8];
        s[0] = a_si + d0.x; s[1] = a_si + d0.y; s[2] = a_si + d0.z; s[3] = a_si + d0.w;
        s[4] = a_si + d1.x; s[5] = a_si + d1.y; s[6] = a_si + d1.z; s[7] = a_si + d1.w;
        int mk[8] = {m0.x, m0.y, m0.z, m0.w, m1.x, m1.y, m1.z, m1.w};
        float mx = -INFINITY;
#pragma unroll
        for (int k = 0; k < 8; ++k) {
            float v = s[k];
            v = (v >= 0.f) ? v : NEG_SLOPE * v;
            v = (mk[k] > 0) ? v : -INFINITY;
            s[k] = v; mx = fmaxf(mx, v);
        }
        mx = wave_red_max(mx);
        float sum = 0.f;
#pragma unroll
        for (int k = 0; k < 8; ++k) { s[k] = __expf(s[k] - mx); sum += s[k]; }
        sum = wave_red_sum(sum);
        float inv = 1.f / sum;
#pragma unroll
        for (int k = 0; k < 8; ++k) p2[i][lane * 8 + k] = s[k] * inv;
    }
    __syncthreads();

    // PV: thread = (i, g, o); 128 j's each
    {
        int i = tid >> 8, g = (tid >> 6) & 3, o = tid & 63;
        float acc = 0.f;
        const float* hb = hp2 + ((size_t)b * NV + g * 128) * 64 + o;
#pragma unroll 8
        for (int jj = 0; jj < 128; ++jj)
            acc += p2[i][g * 128 + jj] * hb[(size_t)jj * 64];
        partial[(i * 4 + g) * 64 + o] = acc;
    }
    __syncthreads();
    if (tid < 128) {
        int i = tid >> 6, o = tid & 63;
        float v = partial[i * 256 + o] + partial[i * 256 + 64 + o]
                + partial[i * 256 + 128 + o] + partial[i * 256 + 192 + o] + b2[o];
        v = (v > 0.f) ? v : (__expf(v) - 1.f);
        lr[i][o] = v;
    }
    __syncthreads();
    if (tid < 64) {
        float v = lr[0][tid] * lr[1][tid];
        vsim[tid] = v;
        d_out[OUT_VSIM + (size_t)b * 64 + tid] = v;
    }
    __syncthreads();
    if (tid < 192) {
        float a = fc1_b[tid];
        for (int k = 0; k < 64; ++k) a += vsim[k] * fc1_w[k * 192 + tid];
        v1[tid] = fmaxf(a, 0.f);
    }
    __syncthreads();
    if (tid < 64) {
        float a = fc2_b[tid];
        for (int k = 0; k < 192; ++k) a += v1[k] * fc2_w[k * 64 + tid];
        v2s[tid] = fmaxf(a, 0.f);
    }
    __syncthreads();
    if (tid == 0) {
        float s0 = fc3_b[0], s1 = fc3_b[1];
        for (int k = 0; k < 64; ++k) { s0 += v2s[k] * fc3_w[k * 2]; s1 += v2s[k] * fc3_w[k * 2 + 1]; }
        float mm = fmaxf(s0, s1);
        float l = logf(__expf(s0 - mm) + __expf(s1 - mm));
        d_out[(size_t)b * 2 + 0] = s0 - mm - l;
        d_out[(size_t)b * 2 + 1] = s1 - mm - l;
    }
}

// ---------------------------------------------------------------------------
extern "C" void kernel_launch(void* const* d_in, const int* in_sizes, int n_in,
                              void* d_out, int out_size, void* d_ws, size_t ws_size,
                              hipStream_t stream) {
    const float* features = (const float*)d_in[0];
    const int*   adj      = (const int*)d_in[1];
    const float* line_emb = (const float*)d_in[5];
    const int*   v_types  = (const int*)d_in[6];
    const float* w1       = (const float*)d_in[7];
    const float* a_src1   = (const float*)d_in[8];
    const float* a_dst1   = (const float*)d_in[9];
    const float* b1       = (const float*)d_in[10];
    const float* w2       = (const float*)d_in[11];
    const float* a_src2   = (const float*)d_in[12];
    const float* a_dst2   = (const float*)d_in[13];
    const float* b2       = (const float*)d_in[14];
    const float* fc1_w    = (const float*)d_in[15];
    const float* fc1_b    = (const float*)d_in[16];
    const float* fc2_w    = (const float*)d_in[17];
    const float* fc2_b    = (const float*)d_in[18];
    const float* fc3_w    = (const float*)d_in[19];
    const float* fc3_b    = (const float*)d_in[20];

    float* out = (float*)d_out;
    float* ws = (float*)d_ws;
    float* hpT = ws;                                    // 32*8*16*512 = 2097152
    float* as1 = hpT + (size_t)BS * NHEAD * 16 * NV;
    float* ad1 = as1 + (size_t)BS * NHEAD * NV;
    float* x1  = ad1 + (size_t)BS * NHEAD * NV;         // 2097152
    float* hp2 = x1 + (size_t)BS * NV * NHEAD * FHID;   // 1048576
    float* as2 = hp2 + (size_t)BS * NV * FOUT;
    float* ad2 = as2 + (size_t)BS * NV;
    float* w2T = ad2 + (size_t)BS * NV;                 // 24576

    hipLaunchKernelGGL(transpose_w2, dim3(96), dim3(256), 0, stream, w2, w2T);

    hipLaunchKernelGGL(gat1_transform_v3, dim3(BS * NHEAD * (NV / 64)), dim3(256), 0, stream,
                       features, line_emb, v_types, w1, a_src1, a_dst1, hpT, as1, ad1);

    hipLaunchKernelGGL(gat1_attn_v3, dim3(BS * NHEAD * (NV / RPB)), dim3(256), 0, stream,
                       hpT, as1, ad1, adj, b1, out + OUT_ATTN, x1);

    hipLaunchKernelGGL(gat2_transform_v2, dim3(BS * (NV / 32)), dim3(256), 0, stream,
                       x1, v_types, w2T, a_src2, a_dst2, hp2, as2, ad2);

    hipLaunchKernelGGL(head_v2, dim3(BS), dim3(512), 0, stream,
                       hp2, as2, ad2, adj, b2,
                       fc1_w, fc1_b, fc2_w, fc2_b, fc3_w, fc3_b, out);
}

// Round 5
// 422.851 us; speedup vs baseline: 1.4505x; 1.1648x over previous
//
#include <hip/hip_runtime.h>
#include <math.h>

#define BS 32
#define NV 512
#define NHEAD 8
#define FHID 16
#define FOUT 64
#define NTYPE 3
#define NEG_SLOPE 0.2f

// d_out float offsets: scores(32*2), v_sim_mul(32*64), attn1(32*8*512*512)
#define OUT_VSIM   64
#define OUT_ATTN   2112

typedef __attribute__((ext_vector_type(8))) short bh8;
typedef __attribute__((ext_vector_type(4))) float f32x4;

__device__ __forceinline__ float wave_red_max(float v) {
#pragma unroll
    for (int m = 1; m < 64; m <<= 1) v = fmaxf(v, __shfl_xor(v, m));
    return v;
}
__device__ __forceinline__ float wave_red_sum(float v) {
#pragma unroll
    for (int m = 1; m < 64; m <<= 1) v += __shfl_xor(v, m);
    return v;
}
__device__ __forceinline__ ushort f2bf(float x) {   // RNE fp32 -> bf16 bits
    union { float f; unsigned u; } v; v.f = x;
    return (ushort)((v.u + 0x7FFFu + ((v.u >> 16) & 1u)) >> 16);
}

// ---------------------------------------------------------------------------
// Kernel W: transpose w2 (3,128,64) -> w2T (3,64,128)
// ---------------------------------------------------------------------------
__global__ __launch_bounds__(256) void transpose_w2(const float* __restrict__ w2,
                                                    float* __restrict__ w2T) {
    int idx = blockIdx.x * 256 + threadIdx.x;
    if (idx < 3 * 64 * 128) {
        int t = idx >> 13, rem = idx & 8191, o = rem >> 7, f = rem & 127;
        w2T[idx] = w2[((size_t)t * 128 + f) * 64 + o];
    }
}

// ---------------------------------------------------------------------------
// Kernel M: compress adj>0 into 512-bit rows. maskb[row][q*4+c] (u64), where
// bit l of entry (q,c) = (adj[row][q*256 + 4l + c] > 0).
// grid = 16384/4 blocks, 256 threads (4 waves, one row each).
// ---------------------------------------------------------------------------
__global__ __launch_bounds__(256) void build_maskbits(
    const int* __restrict__ adj, unsigned long long* __restrict__ maskb)
{
    int row = blockIdx.x * 4 + (threadIdx.x >> 6);
    int lane = threadIdx.x & 63;
    const int4* a4 = (const int4*)(adj + (size_t)row * NV);
#pragma unroll
    for (int q = 0; q < 2; ++q) {
        int4 v = a4[q * 64 + lane];
        unsigned long long b0 = __ballot(v.x > 0);
        unsigned long long b1 = __ballot(v.y > 0);
        unsigned long long b2 = __ballot(v.z > 0);
        unsigned long long b3 = __ballot(v.w > 0);
        if (lane == 0) {
            unsigned long long* dst = maskb + (size_t)row * 8 + q * 4;
            dst[0] = b0; dst[1] = b1; dst[2] = b2; dst[3] = b3;
        }
    }
}

// ---------------------------------------------------------------------------
// Kernel A: layer-1 transform -> hpT_g[bh][o(16)][n(512)] fp32 (transposed),
// plus as1/ad1. grid = BS*NHEAD*8 = 2048 blocks, 256 threads.
// ---------------------------------------------------------------------------
__global__ __launch_bounds__(256) void gat1_transform_v3(
    const float* __restrict__ features, const float* __restrict__ line_emb,
    const int* __restrict__ v_types, const float* __restrict__ w1,
    const float* __restrict__ a_src1, const float* __restrict__ a_dst1,
    float* __restrict__ hpT_g, float* __restrict__ as1, float* __restrict__ ad1)
{
    int chunk = blockIdx.x & 7;
    int bh = blockIdx.x >> 3;
    int b = bh >> 3, h = bh & 7;
    int nb = chunk * 64;
    __shared__ float wT[3 * 16 * 68];   // [t][o][k]
    __shared__ float emb[64 * 68];      // [n][k]
    __shared__ float tpo[16 * 68];      // [o][n_local]
    __shared__ int vt[64];
    int tid = threadIdx.x;

    for (int e = tid; e < 3 * 16 * 64; e += 256) {
        int t = e >> 10, rem = e & 1023, o = rem >> 6, k = rem & 63;
        wT[(t * 16 + o) * 68 + k] = w1[(((size_t)t * 8 + h) * 64 + k) * 16 + o];
    }
    int node0 = b * NV + nb;
    for (int e = tid; e < 64 * 64; e += 256) {
        int n = e >> 6, k = e & 63;
        float v = (k < 32) ? features[(size_t)(node0 + n) * 32 + k]
                           : line_emb[(size_t)(node0 + n) * 32 + (k - 32)];
        emb[n * 68 + k] = v;
    }
    if (tid < 64) vt[tid] = v_types[node0 + tid];
    __syncthreads();

    int o = tid & 15, nl = tid >> 4;
    float asw = a_src1[h * 16 + o], adw = a_dst1[h * 16 + o];
#pragma unroll
    for (int sub = 0; sub < 4; ++sub) {
        int n = sub * 16 + nl;
        int tt = vt[n];
        const float4* ep = (const float4*)&emb[n * 68];
        const float4* wp = (const float4*)&wT[(tt * 16 + o) * 68];
        float acc = 0.f;
#pragma unroll
        for (int kc = 0; kc < 16; ++kc) {
            float4 ev = ep[kc], wv = wp[kc];
            acc += ev.x * wv.x + ev.y * wv.y + ev.z * wv.z + ev.w * wv.w;
        }
        tpo[o * 68 + n] = acc;
        float th = tanhf(acc);
        float ps = th * asw, pd = th * adw;
#pragma unroll
        for (int m = 1; m < 16; m <<= 1) { ps += __shfl_xor(ps, m); pd += __shfl_xor(pd, m); }
        if (o == 0) {
            as1[(size_t)bh * NV + nb + n] = ps;
            ad1[(size_t)bh * NV + nb + n] = pd;
        }
    }
    __syncthreads();
    int o2 = tid >> 4, c = tid & 15;
    float4 v = *(const float4*)&tpo[o2 * 68 + c * 4];
    *(float4*)&hpT_g[((size_t)bh * 16 + o2) * NV + nb + c * 4] = v;
}

// ---------------------------------------------------------------------------
// Kernel B: layer-1 attention. 16 rows/block, 256 threads, MFMA PV.
// Lane owns j = q*256 + lane*4 + (0..3) for q=0,1 -> fully packed 1KB stores.
// grid = BS*NHEAD*(NV/16) = 8192 blocks.
// ---------------------------------------------------------------------------
#define RPB 16
#define HS 520    // ushort row stride: 1040 B -> 2-way bank aliasing only (free)

__global__ __launch_bounds__(256) void gat1_attn_v4(
    const float* __restrict__ hpT_g, const float* __restrict__ as1,
    const float* __restrict__ ad1, const unsigned long long* __restrict__ maskb,
    const float* __restrict__ b1,
    float* __restrict__ attn_out, float* __restrict__ x1)
{
    __shared__ ushort hpb[16 * HS];         // bf16 H^T tile [o][n]
    __shared__ ushort pb[RPB * HS];         // bf16 P tile [row][j]
    __shared__ float partial[4][16][16];    // [wave][col(o)][row]

    int bh = blockIdx.x >> 5;               // b*8+h
    int i0 = (blockIdx.x & 31) * RPB;
    int b = bh >> 3, h = bh & 7;
    int tid = threadIdx.x;

    // stage H^T tile (fp32 -> bf16), coalesced float4 reads
    const float* src = hpT_g + (size_t)bh * 16 * NV;
#pragma unroll
    for (int k = 0; k < 8; ++k) {
        int flat = k * 1024 + tid * 4;
        float4 v = *(const float4*)(src + flat);
        int o = flat >> 9, n = flat & 511;
        ushort4 u; u.x = f2bf(v.x); u.y = f2bf(v.y); u.z = f2bf(v.z); u.w = f2bf(v.w);
        *(ushort4*)&hpb[o * HS + n] = u;
    }

    int wave = tid >> 6, lane = tid & 63;

    const float4* adp4 = (const float4*)(ad1 + (size_t)bh * NV);
    float4 d0 = adp4[lane];            // j = lane*4 + c        (q=0)
    float4 d1 = adp4[64 + lane];       // j = 256 + lane*4 + c  (q=1)
    const unsigned long long* mbb = maskb + (size_t)b * NV * 8;

#pragma unroll
    for (int rr = 0; rr < 4; ++rr) {
        int rl = wave * 4 + rr;
        int i = i0 + rl;
        float a_si = as1[(size_t)bh * NV + i];
        const unsigned long long* mrow = mbb + (size_t)i * 8;
        float s[8];
        s[0] = a_si + d0.x; s[1] = a_si + d0.y; s[2] = a_si + d0.z; s[3] = a_si + d0.w;
        s[4] = a_si + d1.x; s[5] = a_si + d1.y; s[6] = a_si + d1.z; s[7] = a_si + d1.w;
        float mx = -INFINITY;
#pragma unroll
        for (int k2 = 0; k2 < 8; ++k2) {
            float v = s[k2];
            v = (v >= 0.f) ? v : NEG_SLOPE * v;
            v = ((mrow[k2] >> lane) & 1ull) ? v : -INFINITY;
            s[k2] = v;
            mx = fmaxf(mx, v);
        }
        mx = wave_red_max(mx);
        float sum = 0.f;
#pragma unroll
        for (int k2 = 0; k2 < 8; ++k2) { s[k2] = __expf(s[k2] - mx); sum += s[k2]; }
        sum = wave_red_sum(sum);
        float inv = 1.f / sum;
#pragma unroll
        for (int k2 = 0; k2 < 8; ++k2) s[k2] *= inv;

        // exact fp32 attn output: two fully-packed 1KB wave stores
        float4* arow = (float4*)(attn_out + ((size_t)bh * NV + i) * NV);
        float4 pa = {s[0], s[1], s[2], s[3]};
        float4 pv = {s[4], s[5], s[6], s[7]};
        arow[lane] = pa;
        arow[64 + lane] = pv;
        // bf16 P for MFMA
        ushort4 u0 = {f2bf(s[0]), f2bf(s[1]), f2bf(s[2]), f2bf(s[3])};
        ushort4 u1 = {f2bf(s[4]), f2bf(s[5]), f2bf(s[6]), f2bf(s[7])};
        *(ushort4*)&pb[rl * HS + lane * 4] = u0;
        *(ushort4*)&pb[rl * HS + 256 + lane * 4] = u1;
    }
    __syncthreads();

    // PV via MFMA: X[16x16] = P[16x512] @ H[512x16]; wave w does 4 K-chunks.
    int row16 = lane & 15, kg = lane >> 4;
    f32x4 acc = {0.f, 0.f, 0.f, 0.f};
#pragma unroll
    for (int c = 0; c < 4; ++c) {
        int k0 = (wave * 4 + c) * 32 + kg * 8;
        bh8 a = *(const bh8*)&pb[row16 * HS + k0];
        bh8 bf = *(const bh8*)&hpb[row16 * HS + k0];
        acc = __builtin_amdgcn_mfma_f32_16x16x32_bf16(a, bf, acc, 0, 0, 0);
    }
    *(float4*)&partial[wave][row16][kg * 4] = *(float4*)&acc;
    __syncthreads();

    {
        int r = tid >> 4, o = tid & 15;
        float v = partial[0][o][r] + partial[1][o][r]
                + partial[2][o][r] + partial[3][o][r] + b1[o];
        v = (v > 0.f) ? v : (__expf(v) - 1.f);
        x1[((size_t)b * NV + i0 + r) * (NHEAD * FHID) + h * FHID + o] = v;
    }
}

// ---------------------------------------------------------------------------
// Kernel C v3: layer-2 transform, register-blocked 16 nodes/thread.
// grid = 16384/64 = 256 blocks, 256 threads = (o:64, nl:4).
// w2T rows for all 3 types loaded once per fc-chunk, reused by 16 nodes.
// ---------------------------------------------------------------------------
#define CNB 64
__global__ __launch_bounds__(256) void gat2_transform_v3(
    const float* __restrict__ x1, const int* __restrict__ v_types,
    const float* __restrict__ w2T, const float* __restrict__ a_src2,
    const float* __restrict__ a_dst2,
    float* __restrict__ hp2, float* __restrict__ as2, float* __restrict__ ad2)
{
    int node0 = blockIdx.x * CNB;           // flattened node index (b*NV+n)
    __shared__ float xin[CNB * 132];        // stride 132 floats = 33 float4 (16B-aligned)
    __shared__ int vt[CNB];
    int tid = threadIdx.x;
    for (int e = tid; e < CNB * 32; e += 256) {
        int n = e >> 5, fc4 = e & 31;
        *(float4*)&xin[n * 132 + fc4 * 4] =
            *(const float4*)&x1[(size_t)(node0 + n) * 128 + fc4 * 4];
    }
    if (tid < CNB) vt[tid] = v_types[node0 + tid];
    __syncthreads();

    int o = tid & 63, nl = tid >> 6;        // 16 nodes per thread
    int ttn[16];
#pragma unroll
    for (int nn = 0; nn < 16; ++nn) ttn[nn] = vt[nl * 16 + nn];

    float acc[16];
#pragma unroll
    for (int nn = 0; nn < 16; ++nn) acc[nn] = 0.f;

    const float4* w4 = (const float4*)w2T;  // [(t*64+o)*32 + fc4]
    for (int fc4 = 0; fc4 < 32; ++fc4) {
        float4 w0 = w4[(0 * 64 + o) * 32 + fc4];
        float4 wA = w4[(1 * 64 + o) * 32 + fc4];
        float4 wB = w4[(2 * 64 + o) * 32 + fc4];
#pragma unroll
        for (int nn = 0; nn < 16; ++nn) {
            int n = nl * 16 + nn;
            float4 xv = *(const float4*)&xin[n * 132 + fc4 * 4];
            int tt = ttn[nn];
            float4 wv = (tt == 0) ? w0 : (tt == 1) ? wA : wB;
            acc[nn] += xv.x * wv.x + xv.y * wv.y + xv.z * wv.z + xv.w * wv.w;
        }
    }

    float asw = a_src2[o], adw = a_dst2[o];
#pragma unroll
    for (int nn = 0; nn < 16; ++nn) {
        int n = node0 + nl * 16 + nn;
        hp2[(size_t)n * 64 + o] = acc[nn];
        float th = tanhf(acc[nn]);
        float ps = wave_red_sum(th * asw);
        float pd = wave_red_sum(th * adw);
        if (o == 0) { as2[n] = ps; ad2[n] = pd; }
    }
}

// ---------------------------------------------------------------------------
// Kernel D: layer-2 attention rows 0/1 + ELU + v_sim + MLP + log_softmax.
// grid = BS, 512 threads.
// ---------------------------------------------------------------------------
__global__ __launch_bounds__(512) void head_v2(
    const float* __restrict__ hp2, const float* __restrict__ as2,
    const float* __restrict__ ad2, const int* __restrict__ adj,
    const float* __restrict__ b2,
    const float* __restrict__ fc1_w, const float* __restrict__ fc1_b,
    const float* __restrict__ fc2_w, const float* __restrict__ fc2_b,
    const float* __restrict__ fc3_w, const float* __restrict__ fc3_b,
    float* __restrict__ d_out)
{
    int b = blockIdx.x;
    __shared__ float p2[2][NV];
    __shared__ float partial[2 * 4 * 64];
    __shared__ float lr[2][64];
    __shared__ float vsim[64];
    __shared__ float v1[192];
    __shared__ float v2s[64];
    int tid = threadIdx.x, wave = tid >> 6, lane = tid & 63;

    if ((wave & 3) == 0) {          // waves 0 and 4 -> rows 0 and 1
        int i = wave >> 2;
        float a_si = as2[(size_t)b * NV + i];
        const float4* adp4 = (const float4*)(ad2 + (size_t)b * NV);
        float4 d0 = adp4[lane * 2], d1 = adp4[lane * 2 + 1];
        const int4* mrow = (const int4*)(adj + ((size_t)b * NV + i) * NV);
        int4 m0 = mrow[lane * 2], m1 = mrow[lane * 2 + 1];
        float s[8];
        s[0] = a_si + d0.x; s[1] = a_si + d0.y; s[2] = a_si + d0.z; s[3] = a_si + d0.w;
        s[4] = a_si + d1.x; s[5] = a_si + d1.y; s[6] = a_si + d1.z; s[7] = a_si + d1.w;
        int mk[8] = {m0.x, m0.y, m0.z, m0.w, m1.x, m1.y, m1.z, m1.w};
        float mx = -INFINITY;
#pragma unroll
        for (int k = 0; k < 8; ++k) {
            float v = s[k];
            v = (v >= 0.f) ? v : NEG_SLOPE * v;
            v = (mk[k] > 0) ? v : -INFINITY;
            s[k] = v; mx = fmaxf(mx, v);
        }
        mx = wave_red_max(mx);
        float sum = 0.f;
#pragma unroll
        for (int k = 0; k < 8; ++k) { s[k] = __expf(s[k] - mx); sum += s[k]; }
        sum = wave_red_sum(sum);
        float inv = 1.f / sum;
#pragma unroll
        for (int k = 0; k < 8; ++k) p2[i][lane * 8 + k] = s[k] * inv;
    }
    __syncthreads();

    // PV: thread = (i, g, o); 128 j's each
    {
        int i = tid >> 8, g = (tid >> 6) & 3, o = tid & 63;
        float acc = 0.f;
        const float* hb = hp2 + ((size_t)b * NV + g * 128) * 64 + o;
#pragma unroll 8
        for (int jj = 0; jj < 128; ++jj)
            acc += p2[i][g * 128 + jj] * hb[(size_t)jj * 64];
        partial[(i * 4 + g) * 64 + o] = acc;
    }
    __syncthreads();
    if (tid < 128) {
        int i = tid >> 6, o = tid & 63;
        float v = partial[i * 256 + o] + partial[i * 256 + 64 + o]
                + partial[i * 256 + 128 + o] + partial[i * 256 + 192 + o] + b2[o];
        v = (v > 0.f) ? v : (__expf(v) - 1.f);
        lr[i][o] = v;
    }
    __syncthreads();
    if (tid < 64) {
        float v = lr[0][tid] * lr[1][tid];
        vsim[tid] = v;
        d_out[OUT_VSIM + (size_t)b * 64 + tid] = v;
    }
    __syncthreads();
    if (tid < 192) {
        float a = fc1_b[tid];
        for (int k = 0; k < 64; ++k) a += vsim[k] * fc1_w[k * 192 + tid];
        v1[tid] = fmaxf(a, 0.f);
    }
    __syncthreads();
    if (tid < 64) {
        float a = fc2_b[tid];
        for (int k = 0; k < 192; ++k) a += v1[k] * fc2_w[k * 64 + tid];
        v2s[tid] = fmaxf(a, 0.f);
    }
    __syncthreads();
    if (tid == 0) {
        float s0 = fc3_b[0], s1 = fc3_b[1];
        for (int k = 0; k < 64; ++k) { s0 += v2s[k] * fc3_w[k * 2]; s1 += v2s[k] * fc3_w[k * 2 + 1]; }
        float mm = fmaxf(s0, s1);
        float l = logf(__expf(s0 - mm) + __expf(s1 - mm));
        d_out[(size_t)b * 2 + 0] = s0 - mm - l;
        d_out[(size_t)b * 2 + 1] = s1 - mm - l;
    }
}

// ---------------------------------------------------------------------------
extern "C" void kernel_launch(void* const* d_in, const int* in_sizes, int n_in,
                              void* d_out, int out_size, void* d_ws, size_t ws_size,
                              hipStream_t stream) {
    const float* features = (const float*)d_in[0];
    const int*   adj      = (const int*)d_in[1];
    const float* line_emb = (const float*)d_in[5];
    const int*   v_types  = (const int*)d_in[6];
    const float* w1       = (const float*)d_in[7];
    const float* a_src1   = (const float*)d_in[8];
    const float* a_dst1   = (const float*)d_in[9];
    const float* b1       = (const float*)d_in[10];
    const float* w2       = (const float*)d_in[11];
    const float* a_src2   = (const float*)d_in[12];
    const float* a_dst2   = (const float*)d_in[13];
    const float* b2       = (const float*)d_in[14];
    const float* fc1_w    = (const float*)d_in[15];
    const float* fc1_b    = (const float*)d_in[16];
    const float* fc2_w    = (const float*)d_in[17];
    const float* fc2_b    = (const float*)d_in[18];
    const float* fc3_w    = (const float*)d_in[19];
    const float* fc3_b    = (const float*)d_in[20];

    float* out = (float*)d_out;
    float* ws = (float*)d_ws;
    float* hpT = ws;                                    // 32*8*16*512 = 2097152
    float* as1 = hpT + (size_t)BS * NHEAD * 16 * NV;
    float* ad1 = as1 + (size_t)BS * NHEAD * NV;
    float* x1  = ad1 + (size_t)BS * NHEAD * NV;         // 2097152
    float* hp2 = x1 + (size_t)BS * NV * NHEAD * FHID;   // 1048576
    float* as2 = hp2 + (size_t)BS * NV * FOUT;
    float* ad2 = as2 + (size_t)BS * NV;
    float* w2T = ad2 + (size_t)BS * NV;                 // 24576
    unsigned long long* maskb = (unsigned long long*)(w2T + 3 * 64 * 128); // 131072 u64

    hipLaunchKernelGGL(transpose_w2, dim3(96), dim3(256), 0, stream, w2, w2T);

    hipLaunchKernelGGL(build_maskbits, dim3(BS * NV / 4), dim3(256), 0, stream,
                       adj, maskb);

    hipLaunchKernelGGL(gat1_transform_v3, dim3(BS * NHEAD * (NV / 64)), dim3(256), 0, stream,
                       features, line_emb, v_types, w1, a_src1, a_dst1, hpT, as1, ad1);

    hipLaunchKernelGGL(gat1_attn_v4, dim3(BS * NHEAD * (NV / RPB)), dim3(256), 0, stream,
                       hpT, as1, ad1, maskb, b1, out + OUT_ATTN, x1);

    hipLaunchKernelGGL(gat2_transform_v3, dim3(BS * NV / CNB), dim3(256), 0, stream,
                       x1, v_types, w2T, a_src2, a_dst2, hp2, as2, ad2);

    hipLaunchKernelGGL(head_v2, dim3(BS), dim3(512), 0, stream,
                       hp2, as2, ad2, adj, b2,
                       fc1_w, fc1_b, fc2_w, fc2_b, fc3_w, fc3_b, out);
}

// Round 6
// 412.857 us; speedup vs baseline: 1.4856x; 1.0242x over previous
//
#include <hip/hip_runtime.h>
#include <math.h>

#define BS 32
#define NV 512
#define NHEAD 8
#define FHID 16
#define FOUT 64
#define NTYPE 3
#define NEG_SLOPE 0.2f

// d_out float offsets: scores(32*2), v_sim_mul(32*64), attn1(32*8*512*512)
#define OUT_VSIM   64
#define OUT_ATTN   2112

typedef __attribute__((ext_vector_type(8))) short bh8;
typedef __attribute__((ext_vector_type(4))) float f32x4;

__device__ __forceinline__ float wave_red_sum(float v) {
#pragma unroll
    for (int m = 1; m < 64; m <<= 1) v += __shfl_xor(v, m);
    return v;
}
__device__ __forceinline__ ushort f2bf(float x) {   // RNE fp32 -> bf16 bits
    union { float f; unsigned u; } v; v.f = x;
    return (ushort)((v.u + 0x7FFFu + ((v.u >> 16) & 1u)) >> 16);
}

// ---------------------------------------------------------------------------
// Kernel W: transpose w2 (3,128,64) -> w2T (3,64,128)
// ---------------------------------------------------------------------------
__global__ __launch_bounds__(256) void transpose_w2(const float* __restrict__ w2,
                                                    float* __restrict__ w2T) {
    int idx = blockIdx.x * 256 + threadIdx.x;
    if (idx < 3 * 64 * 128) {
        int t = idx >> 13, rem = idx & 8191, o = rem >> 7, f = rem & 127;
        w2T[idx] = w2[((size_t)t * 128 + f) * 64 + o];
    }
}

// ---------------------------------------------------------------------------
// Kernel M: compress adj>0 into 512-bit rows. maskb[row][q*4+c] (u64):
// bit l of entry (q,c) = (adj[row][q*256 + 4l + c] > 0).
// ---------------------------------------------------------------------------
__global__ __launch_bounds__(256) void build_maskbits(
    const int* __restrict__ adj, unsigned long long* __restrict__ maskb)
{
    int row = blockIdx.x * 4 + (threadIdx.x >> 6);
    int lane = threadIdx.x & 63;
    const int4* a4 = (const int4*)(adj + (size_t)row * NV);
#pragma unroll
    for (int q = 0; q < 2; ++q) {
        int4 v = a4[q * 64 + lane];
        unsigned long long b0 = __ballot(v.x > 0);
        unsigned long long b1 = __ballot(v.y > 0);
        unsigned long long b2 = __ballot(v.z > 0);
        unsigned long long b3 = __ballot(v.w > 0);
        if (lane == 0) {
            unsigned long long* dst = maskb + (size_t)row * 8 + q * 4;
            dst[0] = b0; dst[1] = b1; dst[2] = b2; dst[3] = b3;
        }
    }
}

// ---------------------------------------------------------------------------
// Kernel A: layer-1 transform -> hpT_bf[bh][o(16)][n(512)] bf16 (transposed),
// plus as1/ad1. grid = BS*NHEAD*8 = 2048 blocks, 256 threads.
// ---------------------------------------------------------------------------
__global__ __launch_bounds__(256) void gat1_transform_v4(
    const float* __restrict__ features, const float* __restrict__ line_emb,
    const int* __restrict__ v_types, const float* __restrict__ w1,
    const float* __restrict__ a_src1, const float* __restrict__ a_dst1,
    ushort* __restrict__ hpT_bf, float* __restrict__ as1, float* __restrict__ ad1)
{
    int chunk = blockIdx.x & 7;
    int bh = blockIdx.x >> 3;
    int b = bh >> 3, h = bh & 7;
    int nb = chunk * 64;
    __shared__ float wT[3 * 16 * 68];   // [t][o][k]
    __shared__ float emb[64 * 68];      // [n][k]
    __shared__ float tpo[16 * 68];      // [o][n_local]
    __shared__ int vt[64];
    int tid = threadIdx.x;

    for (int e = tid; e < 3 * 16 * 64; e += 256) {
        int t = e >> 10, rem = e & 1023, o = rem >> 6, k = rem & 63;
        wT[(t * 16 + o) * 68 + k] = w1[(((size_t)t * 8 + h) * 64 + k) * 16 + o];
    }
    int node0 = b * NV + nb;
    for (int e = tid; e < 64 * 64; e += 256) {
        int n = e >> 6, k = e & 63;
        float v = (k < 32) ? features[(size_t)(node0 + n) * 32 + k]
                           : line_emb[(size_t)(node0 + n) * 32 + (k - 32)];
        emb[n * 68 + k] = v;
    }
    if (tid < 64) vt[tid] = v_types[node0 + tid];
    __syncthreads();

    int o = tid & 15, nl = tid >> 4;
    float asw = a_src1[h * 16 + o], adw = a_dst1[h * 16 + o];
#pragma unroll
    for (int sub = 0; sub < 4; ++sub) {
        int n = sub * 16 + nl;
        int tt = vt[n];
        const float4* ep = (const float4*)&emb[n * 68];
        const float4* wp = (const float4*)&wT[(tt * 16 + o) * 68];
        float acc = 0.f;
#pragma unroll
        for (int kc = 0; kc < 16; ++kc) {
            float4 ev = ep[kc], wv = wp[kc];
            acc += ev.x * wv.x + ev.y * wv.y + ev.z * wv.z + ev.w * wv.w;
        }
        tpo[o * 68 + n] = acc;
        float th = tanhf(acc);
        float ps = th * asw, pd = th * adw;
#pragma unroll
        for (int m = 1; m < 16; m <<= 1) { ps += __shfl_xor(ps, m); pd += __shfl_xor(pd, m); }
        if (o == 0) {
            as1[(size_t)bh * NV + nb + n] = ps;
            ad1[(size_t)bh * NV + nb + n] = pd;
        }
    }
    __syncthreads();
    // coalesced transposed bf16 write
    int o2 = tid >> 4, c = tid & 15;
    float4 v = *(const float4*)&tpo[o2 * 68 + c * 4];
    ushort4 u; u.x = f2bf(v.x); u.y = f2bf(v.y); u.z = f2bf(v.z); u.w = f2bf(v.w);
    *(ushort4*)&hpT_bf[((size_t)bh * 16 + o2) * NV + nb + c * 4] = u;
}

// ---------------------------------------------------------------------------
// Kernel B v5: layer-1 attention. 16 rows/block, 256 threads, MFMA PV.
// No-max softmax (scores provably <= 19.1) + batched ILP-4 sum reductions.
// grid = BS*NHEAD*(NV/16) = 8192 blocks.
// ---------------------------------------------------------------------------
#define RPB 16
#define HS 520    // ushort row stride: 1040 B -> 2-way bank aliasing only (free)

__global__ __launch_bounds__(256) void gat1_attn_v5(
    const ushort* __restrict__ hpT_bf, const float* __restrict__ as1,
    const float* __restrict__ ad1, const unsigned long long* __restrict__ maskb,
    const float* __restrict__ b1,
    float* __restrict__ attn_out, float* __restrict__ x1)
{
    __shared__ ushort hpb[16 * HS];         // bf16 H^T tile [o][n]
    __shared__ ushort pb[RPB * HS];         // bf16 P tile [row][j]
    __shared__ float partial[4][16][16];    // [wave][col(o)][row]

    int bh = blockIdx.x >> 5;               // b*8+h
    int i0 = (blockIdx.x & 31) * RPB;
    int b = bh >> 3, h = bh & 7;
    int tid = threadIdx.x;

    // stage bf16 H^T tile: 4 x 16B loads/thread, no conversion
    const ushort* src = hpT_bf + (size_t)bh * 16 * NV;
#pragma unroll
    for (int k = 0; k < 4; ++k) {
        int flat = k * 2048 + tid * 8;
        uint4 v = *(const uint4*)(src + flat);
        int o = flat >> 9, n = flat & 511;
        *(uint4*)&hpb[o * HS + n] = v;
    }

    int wave = tid >> 6, lane = tid & 63;

    const float4* adp4 = (const float4*)(ad1 + (size_t)bh * NV);
    float4 d0 = adp4[lane];            // j = lane*4 + c        (q=0)
    float4 d1 = adp4[64 + lane];       // j = 256 + lane*4 + c  (q=1)
    const unsigned long long* mbb = maskb + (size_t)b * NV * 8;

    // Phase 1: exps for all 4 rows (independent, pipelined)
    float ex[4][8];
    float psum[4];
#pragma unroll
    for (int rr = 0; rr < 4; ++rr) {
        int i = i0 + wave * 4 + rr;
        float a_si = as1[(size_t)bh * NV + i];             // scalar load
        const unsigned long long* mrow = mbb + (size_t)i * 8;  // scalar loads
        float s[8];
        s[0] = a_si + d0.x; s[1] = a_si + d0.y; s[2] = a_si + d0.z; s[3] = a_si + d0.w;
        s[4] = a_si + d1.x; s[5] = a_si + d1.y; s[6] = a_si + d1.z; s[7] = a_si + d1.w;
        float ps = 0.f;
#pragma unroll
        for (int k2 = 0; k2 < 8; ++k2) {
            float v = s[k2];
            v = fmaxf(v, NEG_SLOPE * v);                   // leaky relu
            float e = __expf(v);                           // bounded: v <= 19.1
            e = ((mrow[k2] >> lane) & 1ull) ? e : 0.f;     // mask -> exp(-inf)=0
            ex[rr][k2] = e;
            ps += e;
        }
        psum[rr] = ps;
    }
    // Phase 2: 4 independent sum reductions (ILP hides shuffle latency)
#pragma unroll
    for (int rr = 0; rr < 4; ++rr) psum[rr] = wave_red_sum(psum[rr]);
    // Phase 3: normalize, store fp32 attn + bf16 P
#pragma unroll
    for (int rr = 0; rr < 4; ++rr) {
        int rl = wave * 4 + rr;
        int i = i0 + rl;
        float inv = 1.f / psum[rr];
        float4 pa = {ex[rr][0] * inv, ex[rr][1] * inv, ex[rr][2] * inv, ex[rr][3] * inv};
        float4 pv = {ex[rr][4] * inv, ex[rr][5] * inv, ex[rr][6] * inv, ex[rr][7] * inv};
        float4* arow = (float4*)(attn_out + ((size_t)bh * NV + i) * NV);
        arow[lane] = pa;
        arow[64 + lane] = pv;
        ushort4 u0 = {f2bf(pa.x), f2bf(pa.y), f2bf(pa.z), f2bf(pa.w)};
        ushort4 u1 = {f2bf(pv.x), f2bf(pv.y), f2bf(pv.z), f2bf(pv.w)};
        *(ushort4*)&pb[rl * HS + lane * 4] = u0;
        *(ushort4*)&pb[rl * HS + 256 + lane * 4] = u1;
    }
    __syncthreads();

    // PV via MFMA: X[16x16] = P[16x512] @ H[512x16]; wave w does 4 K-chunks.
    int row16 = lane & 15, kg = lane >> 4;
    f32x4 acc = {0.f, 0.f, 0.f, 0.f};
#pragma unroll
    for (int c = 0; c < 4; ++c) {
        int k0 = (wave * 4 + c) * 32 + kg * 8;
        bh8 a = *(const bh8*)&pb[row16 * HS + k0];
        bh8 bf = *(const bh8*)&hpb[row16 * HS + k0];
        acc = __builtin_amdgcn_mfma_f32_16x16x32_bf16(a, bf, acc, 0, 0, 0);
    }
    *(float4*)&partial[wave][row16][kg * 4] = *(float4*)&acc;
    __syncthreads();

    {
        int r = tid >> 4, o = tid & 15;
        float v = partial[0][o][r] + partial[1][o][r]
                + partial[2][o][r] + partial[3][o][r] + b1[o];
        v = (v > 0.f) ? v : (__expf(v) - 1.f);
        x1[((size_t)b * NV + i0 + r) * (NHEAD * FHID) + h * FHID + o] = v;
    }
}

// ---------------------------------------------------------------------------
// Kernel C v3: layer-2 transform, register-blocked 16 nodes/thread.
// grid = 16384/64 = 256 blocks, 256 threads = (o:64, nl:4).
// ---------------------------------------------------------------------------
#define CNB 64
__global__ __launch_bounds__(256) void gat2_transform_v3(
    const float* __restrict__ x1, const int* __restrict__ v_types,
    const float* __restrict__ w2T, const float* __restrict__ a_src2,
    const float* __restrict__ a_dst2,
    float* __restrict__ hp2, float* __restrict__ as2, float* __restrict__ ad2)
{
    int node0 = blockIdx.x * CNB;
    __shared__ float xin[CNB * 132];
    __shared__ int vt[CNB];
    int tid = threadIdx.x;
    for (int e = tid; e < CNB * 32; e += 256) {
        int n = e >> 5, fc4 = e & 31;
        *(float4*)&xin[n * 132 + fc4 * 4] =
            *(const float4*)&x1[(size_t)(node0 + n) * 128 + fc4 * 4];
    }
    if (tid < CNB) vt[tid] = v_types[node0 + tid];
    __syncthreads();

    int o = tid & 63, nl = tid >> 6;
    int ttn[16];
#pragma unroll
    for (int nn = 0; nn < 16; ++nn) ttn[nn] = vt[nl * 16 + nn];

    float acc[16];
#pragma unroll
    for (int nn = 0; nn < 16; ++nn) acc[nn] = 0.f;

    const float4* w4 = (const float4*)w2T;
    for (int fc4 = 0; fc4 < 32; ++fc4) {
        float4 w0 = w4[(0 * 64 + o) * 32 + fc4];
        float4 wA = w4[(1 * 64 + o) * 32 + fc4];
        float4 wB = w4[(2 * 64 + o) * 32 + fc4];
#pragma unroll
        for (int nn = 0; nn < 16; ++nn) {
            int n = nl * 16 + nn;
            float4 xv = *(const float4*)&xin[n * 132 + fc4 * 4];
            int tt = ttn[nn];
            float4 wv = (tt == 0) ? w0 : (tt == 1) ? wA : wB;
            acc[nn] += xv.x * wv.x + xv.y * wv.y + xv.z * wv.z + xv.w * wv.w;
        }
    }

    float asw = a_src2[o], adw = a_dst2[o];
#pragma unroll
    for (int nn = 0; nn < 16; ++nn) {
        int n = node0 + nl * 16 + nn;
        hp2[(size_t)n * 64 + o] = acc[nn];
        float th = tanhf(acc[nn]);
        float ps = wave_red_sum(th * asw);
        float pd = wave_red_sum(th * adw);
        if (o == 0) { as2[n] = ps; ad2[n] = pd; }
    }
}

// ---------------------------------------------------------------------------
// Kernel D: layer-2 attention rows 0/1 + ELU + v_sim + MLP + log_softmax.
// No-max softmax (scores <= 38.8, exp <= 7e16 — fp32-safe).
// grid = BS, 512 threads.
// ---------------------------------------------------------------------------
__global__ __launch_bounds__(512) void head_v3(
    const float* __restrict__ hp2, const float* __restrict__ as2,
    const float* __restrict__ ad2, const int* __restrict__ adj,
    const float* __restrict__ b2,
    const float* __restrict__ fc1_w, const float* __restrict__ fc1_b,
    const float* __restrict__ fc2_w, const float* __restrict__ fc2_b,
    const float* __restrict__ fc3_w, const float* __restrict__ fc3_b,
    float* __restrict__ d_out)
{
    int b = blockIdx.x;
    __shared__ float p2[2][NV];
    __shared__ float partial[2 * 4 * 64];
    __shared__ float lr[2][64];
    __shared__ float vsim[64];
    __shared__ float v1[192];
    __shared__ float v2s[64];
    int tid = threadIdx.x, wave = tid >> 6, lane = tid & 63;

    if ((wave & 3) == 0) {          // waves 0 and 4 -> rows 0 and 1
        int i = wave >> 2;
        float a_si = as2[(size_t)b * NV + i];
        const float4* adp4 = (const float4*)(ad2 + (size_t)b * NV);
        float4 d0 = adp4[lane * 2], d1 = adp4[lane * 2 + 1];
        const int4* mrow = (const int4*)(adj + ((size_t)b * NV + i) * NV);
        int4 m0 = mrow[lane * 2], m1 = mrow[lane * 2 + 1];
        float s[8];
        s[0] = a_si + d0.x; s[1] = a_si + d0.y; s[2] = a_si + d0.z; s[3] = a_si + d0.w;
        s[4] = a_si + d1.x; s[5] = a_si + d1.y; s[6] = a_si + d1.z; s[7] = a_si + d1.w;
        int mk[8] = {m0.x, m0.y, m0.z, m0.w, m1.x, m1.y, m1.z, m1.w};
        float sum = 0.f;
#pragma unroll
        for (int k = 0; k < 8; ++k) {
            float v = s[k];
            v = fmaxf(v, NEG_SLOPE * v);
            float e = __expf(v);
            e = (mk[k] > 0) ? e : 0.f;
            s[k] = e; sum += e;
        }
        sum = wave_red_sum(sum);
        float inv = 1.f / sum;
#pragma unroll
        for (int k = 0; k < 8; ++k) p2[i][lane * 8 + k] = s[k] * inv;
    }
    __syncthreads();

    // PV: thread = (i, g, o); 128 j's each
    {
        int i = tid >> 8, g = (tid >> 6) & 3, o = tid & 63;
        float acc = 0.f;
        const float* hb = hp2 + ((size_t)b * NV + g * 128) * 64 + o;
#pragma unroll 8
        for (int jj = 0; jj < 128; ++jj)
            acc += p2[i][g * 128 + jj] * hb[(size_t)jj * 64];
        partial[(i * 4 + g) * 64 + o] = acc;
    }
    __syncthreads();
    if (tid < 128) {
        int i = tid >> 6, o = tid & 63;
        float v = partial[i * 256 + o] + partial[i * 256 + 64 + o]
                + partial[i * 256 + 128 + o] + partial[i * 256 + 192 + o] + b2[o];
        v = (v > 0.f) ? v : (__expf(v) - 1.f);
        lr[i][o] = v;
    }
    __syncthreads();
    if (tid < 64) {
        float v = lr[0][tid] * lr[1][tid];
        vsim[tid] = v;
        d_out[OUT_VSIM + (size_t)b * 64 + tid] = v;
    }
    __syncthreads();
    if (tid < 192) {
        float a = fc1_b[tid];
        for (int k = 0; k < 64; ++k) a += vsim[k] * fc1_w[k * 192 + tid];
        v1[tid] = fmaxf(a, 0.f);
    }
    __syncthreads();
    if (tid < 64) {
        float a = fc2_b[tid];
        for (int k = 0; k < 192; ++k) a += v1[k] * fc2_w[k * 64 + tid];
        v2s[tid] = fmaxf(a, 0.f);
    }
    __syncthreads();
    if (tid == 0) {
        float s0 = fc3_b[0], s1 = fc3_b[1];
        for (int k = 0; k < 64; ++k) { s0 += v2s[k] * fc3_w[k * 2]; s1 += v2s[k] * fc3_w[k * 2 + 1]; }
        float mm = fmaxf(s0, s1);
        float l = logf(__expf(s0 - mm) + __expf(s1 - mm));
        d_out[(size_t)b * 2 + 0] = s0 - mm - l;
        d_out[(size_t)b * 2 + 1] = s1 - mm - l;
    }
}

// ---------------------------------------------------------------------------
extern "C" void kernel_launch(void* const* d_in, const int* in_sizes, int n_in,
                              void* d_out, int out_size, void* d_ws, size_t ws_size,
                              hipStream_t stream) {
    const float* features = (const float*)d_in[0];
    const int*   adj      = (const int*)d_in[1];
    const float* line_emb = (const float*)d_in[5];
    const int*   v_types  = (const int*)d_in[6];
    const float* w1       = (const float*)d_in[7];
    const float* a_src1   = (const float*)d_in[8];
    const float* a_dst1   = (const float*)d_in[9];
    const float* b1       = (const float*)d_in[10];
    const float* w2       = (const float*)d_in[11];
    const float* a_src2   = (const float*)d_in[12];
    const float* a_dst2   = (const float*)d_in[13];
    const float* b2       = (const float*)d_in[14];
    const float* fc1_w    = (const float*)d_in[15];
    const float* fc1_b    = (const float*)d_in[16];
    const float* fc2_w    = (const float*)d_in[17];
    const float* fc2_b    = (const float*)d_in[18];
    const float* fc3_w    = (const float*)d_in[19];
    const float* fc3_b    = (const float*)d_in[20];

    float* out = (float*)d_out;
    float* ws = (float*)d_ws;
    ushort* hpT = (ushort*)ws;                          // 32*8*16*512 ushorts = 4MB
    float* as1 = ws + (size_t)BS * NHEAD * 16 * NV / 2; // after 1M floats-worth
    float* ad1 = as1 + (size_t)BS * NHEAD * NV;
    float* x1  = ad1 + (size_t)BS * NHEAD * NV;         // 2097152 floats
    float* hp2 = x1 + (size_t)BS * NV * NHEAD * FHID;   // 1048576 floats
    float* as2 = hp2 + (size_t)BS * NV * FOUT;
    float* ad2 = as2 + (size_t)BS * NV;
    float* w2T = ad2 + (size_t)BS * NV;                 // 24576 floats
    unsigned long long* maskb = (unsigned long long*)(w2T + 3 * 64 * 128); // 131072 u64

    hipLaunchKernelGGL(transpose_w2, dim3(96), dim3(256), 0, stream, w2, w2T);

    hipLaunchKernelGGL(build_maskbits, dim3(BS * NV / 4), dim3(256), 0, stream,
                       adj, maskb);

    hipLaunchKernelGGL(gat1_transform_v4, dim3(BS * NHEAD * (NV / 64)), dim3(256), 0, stream,
                       features, line_emb, v_types, w1, a_src1, a_dst1, hpT, as1, ad1);

    hipLaunchKernelGGL(gat1_attn_v5, dim3(BS * NHEAD * (NV / RPB)), dim3(256), 0, stream,
                       hpT, as1, ad1, maskb, b1, out + OUT_ATTN, x1);

    hipLaunchKernelGGL(gat2_transform_v3, dim3(BS * NV / CNB), dim3(256), 0, stream,
                       x1, v_types, w2T, a_src2, a_dst2, hp2, as2, ad2);

    hipLaunchKernelGGL(head_v3, dim3(BS), dim3(512), 0, stream,
                       hp2, as2, ad2, adj, b2,
                       fc1_w, fc1_b, fc2_w, fc2_b, fc3_w, fc3_b, out);
}